// Round 1
// baseline (603.577 us; speedup 1.0000x reference)
//
#include <hip/hip_runtime.h>

#define NSLOPE 0.2f

// ======================= CSR build (per-launch; ws is re-poisoned) ==========
__global__ void init_cnt_kernel(int* cnt, int n){
  int i = blockIdx.x*blockDim.x + threadIdx.x;
  if (i < n) cnt[i] = 1;                       // count the self-loop up front
}

__global__ void hist_kernel(const int* __restrict__ ei, int E, int* cnt){
  int e = blockIdx.x*blockDim.x + threadIdx.x;
  if (e < E) atomicAdd(&cnt[ei[E + e]], 1);    // dst row of edge_index
}

// single-block chunked Hillis-Steele exclusive scan over N counts
__global__ void scan_kernel(const int* __restrict__ cnt, int* __restrict__ rowptr,
                            int* __restrict__ cursor, int n){
  __shared__ int sdata[1024];
  __shared__ int run_s;
  int t = threadIdx.x;
  if (t == 0) run_s = 0;
  __syncthreads();
  for (int base = 0; base < n; base += 1024){
    int idx = base + t;
    int v = (idx < n) ? cnt[idx] : 0;
    sdata[t] = v;
    __syncthreads();
    for (int off = 1; off < 1024; off <<= 1){
      int x = (t >= off) ? sdata[t - off] : 0;
      __syncthreads();
      sdata[t] += x;
      __syncthreads();
    }
    int run = run_s;
    int excl = run + sdata[t] - v;
    if (idx < n){ rowptr[idx] = excl; cursor[idx] = excl; }
    __syncthreads();
    if (t == 1023) run_s = run + sdata[1023];
    __syncthreads();
  }
  if (t == 0) rowptr[n] = run_s;
}

__global__ void fill_kernel(const int* __restrict__ ei, int E, int n,
                            int* cursor, int* __restrict__ col){
  int i = blockIdx.x*blockDim.x + threadIdx.x;
  if (i < E){
    int s = ei[i], d = ei[E + i];
    int slot = atomicAdd(&cursor[d], 1);
    col[slot] = s;
  } else if (i < E + n){
    int v = i - E;                             // self loop (v -> v)
    int slot = atomicAdd(&cursor[v], 1);
    col[slot] = v;
  }
}

// ======================= fp32 tiled GEMM: C[M,Nc] = A[M,K] @ B[K,Nc] ========
// 64x64 block tile, 256 threads, 4x4 per thread, BK=16 staged in LDS.
#define BM 64
#define BN 64
#define BK 16
#define LDA (BM + 4)
#define LDB (BN + 4)
__global__ __launch_bounds__(256) void gemm_kernel(const float* __restrict__ A,
    const float* __restrict__ B, float* __restrict__ C, int M, int Nc, int K){
  __shared__ float As[BK][LDA];   // [k][m], padded to dodge store conflicts
  __shared__ float Bs[BK][LDB];   // [k][n], pad 4 keeps float4 alignment
  int t  = threadIdx.x;
  int bm = blockIdx.x * BM;
  int bn = blockIdx.y * BN;
  int tx = t & 15, ty = t >> 4;
  int arow = t >> 2, ak = (t & 3) << 2;      // A: float4 per thread (64x16)
  int bkr  = t >> 4, bnc = (t & 15) << 2;    // B: float4 per thread (16x64)
  float acc[4][4] = {};
  for (int k0 = 0; k0 < K; k0 += BK){
    int grow = bm + arow;
    float4 av = make_float4(0.f,0.f,0.f,0.f);
    if (grow < M) av = *(const float4*)(A + (size_t)grow*K + k0 + ak);
    As[ak+0][arow] = av.x; As[ak+1][arow] = av.y;
    As[ak+2][arow] = av.z; As[ak+3][arow] = av.w;
    float4 bv = *(const float4*)(B + (size_t)(k0 + bkr)*Nc + bn + bnc);
    *(float4*)&Bs[bkr][bnc] = bv;
    __syncthreads();
#pragma unroll
    for (int k = 0; k < BK; k++){
      float a[4], b[4];
#pragma unroll
      for (int j = 0; j < 4; j++){ a[j] = As[k][ty*4 + j]; b[j] = Bs[k][tx*4 + j]; }
#pragma unroll
      for (int i = 0; i < 4; i++)
#pragma unroll
        for (int j = 0; j < 4; j++) acc[i][j] += a[i]*b[j];
    }
    __syncthreads();
  }
#pragma unroll
  for (int i = 0; i < 4; i++){
    int row = bm + ty*4 + i;
    if (row < M){
      float4 v = make_float4(acc[i][0], acc[i][1], acc[i][2], acc[i][3]);
      *(float4*)(C + (size_t)row*Nc + bn + tx*4) = v;
    }
  }
}

// ============== attention coefficients: al_s/al_d[n,h] = <h_row, a> =========
template<int H, int CH>
__global__ __launch_bounds__(128) void attn_coef_kernel(
    const float* __restrict__ Hm, const float* __restrict__ asrc,
    const float* __restrict__ adst, float* __restrict__ al_s,
    float* __restrict__ al_d){
  int b = blockIdx.x;                 // n*H + h
  int n = b / H, h = b % H;
  const float* row = Hm + (size_t)n*(H*CH) + (size_t)h*CH;
  int t = threadIdx.x;
  float ss = 0.f, sd = 0.f;
  for (int c = t; c < CH; c += 128){
    float v = row[c];
    ss += v * asrc[h*CH + c];
    sd += v * adst[h*CH + c];
  }
#pragma unroll
  for (int off = 32; off > 0; off >>= 1){
    ss += __shfl_down(ss, off);
    sd += __shfl_down(sd, off);
  }
  __shared__ float r0[2], r1[2];
  int wave = t >> 6, lane = t & 63;
  if (lane == 0){ r0[wave] = ss; r1[wave] = sd; }
  __syncthreads();
  if (t == 0){ al_s[b] = r0[0] + r0[1]; al_d[b] = r1[0] + r1[1]; }
}

// ====== per-dst segment softmax + weighted aggregation + bias (+ReLU) =======
// one block (256 thr) per destination node; two-pass softmax (max, exp+sum),
// 64-edge chunks of exp-coefs staged in LDS; each thread owns F/256 channels.
template<int H, int CH, bool RELU>
__global__ __launch_bounds__(256) void aggregate_kernel(
    const float* __restrict__ Hm, const float* __restrict__ al_s,
    const float* __restrict__ al_d, const int* __restrict__ rowptr,
    const int* __restrict__ col, const float* __restrict__ bias,
    float* __restrict__ outF){
  constexpr int F  = H * CH;      // 512
  constexpr int PT = F / 256;     // 2 channels per thread
  __shared__ float red[256];
  __shared__ float e_lds[64][H];
  __shared__ int   src_lds[64];

  int d = blockIdx.x;
  int t = threadIdx.x;
  int start = rowptr[d], end = rowptr[d + 1];

  float ald[H];
#pragma unroll
  for (int h = 0; h < H; h++) ald[h] = al_d[(size_t)d*H + h];

  // ---- pass 1: per-head max of leaky_relu(al_s[src]+al_d[d]) ----
  float mx[H];
#pragma unroll
  for (int h = 0; h < H; h++) mx[h] = -1e30f;
  for (int e = start + t; e < end; e += 256){
    int s = col[e];
#pragma unroll
    for (int h = 0; h < H; h++){
      float v = al_s[(size_t)s*H + h] + ald[h];
      v = (v > 0.f) ? v : NSLOPE * v;
      mx[h] = fmaxf(mx[h], v);
    }
  }
#pragma unroll
  for (int h = 0; h < H; h++){
    red[t] = mx[h]; __syncthreads();
    for (int off = 128; off > 0; off >>= 1){
      if (t < off) red[t] = fmaxf(red[t], red[t + off]);
      __syncthreads();
    }
    mx[h] = red[0]; __syncthreads();
  }

  // ---- pass 2: e = exp(logit-max); accumulate e*h[src] and Σe ----
  int hh[PT];
#pragma unroll
  for (int p = 0; p < PT; p++) hh[p] = (t + p*256) / CH;
  float acc[PT] = {};
  float lsum[H] = {};
  for (int c0 = start; c0 < end; c0 += 64){
    int cnt = min(64, end - c0);
    if (t < cnt){
      int s = col[c0 + t];
      src_lds[t] = s;
#pragma unroll
      for (int h = 0; h < H; h++){
        float v = al_s[(size_t)s*H + h] + ald[h];
        v = (v > 0.f) ? v : NSLOPE * v;
        float ev = __expf(v - mx[h]);
        e_lds[t][h] = ev;
        lsum[h] += ev;
      }
    }
    __syncthreads();
    for (int i = 0; i < cnt; i++){
      const float* hrow = Hm + (size_t)src_lds[i] * F;
#pragma unroll
      for (int p = 0; p < PT; p++)
        acc[p] += e_lds[i][hh[p]] * hrow[t + p*256];
    }
    __syncthreads();
  }
#pragma unroll
  for (int h = 0; h < H; h++){
    red[t] = lsum[h]; __syncthreads();
    for (int off = 128; off > 0; off >>= 1){
      if (t < off) red[t] += red[t + off];
      __syncthreads();
    }
    lsum[h] = red[0]; __syncthreads();
  }
#pragma unroll
  for (int p = 0; p < PT; p++){
    int c = t + p*256;
    float v = acc[p] / lsum[hh[p]] + bias[c];
    if (RELU) v = fmaxf(v, 0.f);
    outF[(size_t)d*F + c] = v;
  }
}

// =========================== launch =========================================
extern "C" void kernel_launch(void* const* d_in, const int* in_sizes, int n_in,
                              void* d_out, int out_size, void* d_ws, size_t ws_size,
                              hipStream_t stream){
  const float* x   = (const float*)d_in[0];
  const int*   ei  = (const int*)  d_in[1];
  const float* W1  = (const float*)d_in[2];
  const float* as1 = (const float*)d_in[3];
  const float* ad1 = (const float*)d_in[4];
  const float* b1  = (const float*)d_in[5];
  const float* W2  = (const float*)d_in[6];
  const float* as2 = (const float*)d_in[7];
  const float* ad2 = (const float*)d_in[8];
  const float* b2  = (const float*)d_in[9];
  const float* W3  = (const float*)d_in[10];
  const float* as3 = (const float*)d_in[11];
  const float* ad3 = (const float*)d_in[12];
  const float* b3  = (const float*)d_in[13];
  float* out = (float*)d_out;

  const int N = in_sizes[0] / 128;   // 10000
  const int E = in_sizes[1] / 2;     // 320000
  const int F = 512;

  // workspace carve-up
  float* Hmat = (float*)d_ws;                 // N*512
  float* feat = Hmat + (size_t)N*F;           // N*512
  float* al_s = feat + (size_t)N*F;           // N*4
  float* al_d = al_s + (size_t)N*4;           // N*4
  int*   cnt    = (int*)(al_d + (size_t)N*4); // N
  int*   rowptr = cnt + N;                    // N+1
  int*   cursor = rowptr + N + 1;             // N
  int*   col    = cursor + N;                 // E+N

  // CSR by destination
  init_cnt_kernel<<<(N+255)/256, 256, 0, stream>>>(cnt, N);
  hist_kernel<<<(E+255)/256, 256, 0, stream>>>(ei, E, cnt);
  scan_kernel<<<1, 1024, 0, stream>>>(cnt, rowptr, cursor, N);
  fill_kernel<<<(E+N+255)/256, 256, 0, stream>>>(ei, E, N, cursor, col);

  dim3 ggrid((N + BM - 1)/BM, F/BN);

  // ---- layer 1: x[N,128] @ W1[128,512] ----
  gemm_kernel<<<ggrid, 256, 0, stream>>>(x, W1, Hmat, N, F, 128);
  attn_coef_kernel<4,128><<<N*4, 128, 0, stream>>>(Hmat, as1, ad1, al_s, al_d);
  aggregate_kernel<4,128,true><<<N, 256, 0, stream>>>(Hmat, al_s, al_d, rowptr, col, b1, feat);

  // ---- layer 2: feat[N,512] @ W2[512,512] ----
  gemm_kernel<<<ggrid, 256, 0, stream>>>(feat, W2, Hmat, N, F, 512);
  attn_coef_kernel<4,128><<<N*4, 128, 0, stream>>>(Hmat, as2, ad2, al_s, al_d);
  aggregate_kernel<4,128,true><<<N, 256, 0, stream>>>(Hmat, al_s, al_d, rowptr, col, b2, feat);

  // ---- layer 3: feat[N,512] @ W3[512,512], heads=1 ----
  gemm_kernel<<<ggrid, 256, 0, stream>>>(feat, W3, Hmat, N, F, 512);
  attn_coef_kernel<1,512><<<N, 128, 0, stream>>>(Hmat, as3, ad3, al_s, al_d);
  aggregate_kernel<1,512,false><<<N, 256, 0, stream>>>(Hmat, al_s, al_d, rowptr, col, b3, out);
}